// Round 15
// baseline (112.516 us; speedup 1.0000x reference)
//
#include <hip/hip_runtime.h>

// Problem constants
#define MD 4
#define PATCH 9          // 2*MD+1
#define NBAND 256        // band-compute blocks: (b, ty) = 4 * 64
#define NZERO 1024       // zero-streaming blocks
#define BT 1024          // threads per block (16 waves)
// feat1/feat2: (4, 256, 64, 64) fp32
// out: (4, 4096, 64, 64) fp32 = 256 MB
//
// out[b, ty*64+tx, y, x] = sum_c f1[b,c,y,x] * f2[b,c,ty,tx]  if |ty-y|<=4 && |tx-x|<=4, else 0.
//
// R15 = R11 (85us best) with ONE change: f2 staged as CHANNEL-PAIRED float2 rows.
//   sF2[c2][p] = {f2[2c2][p-4], f2[2c2+1][p-4]}, p in [0,72), 4-float2 zero margins.
//   The 9-value shifted window is read as 9 ds_read_b64 serving TWO channels each:
//   halves the LDS instruction count (R11's band phase was LDS-issue-bound:
//   16 waves x 576 ds_read_b32 x ~5.8cyc x 2 blocks/CU ~= 44us, matching measurement).
// Zero-stream, union LDS, store-then-add merge, writeout: R11-verbatim.

template<int ND>
__device__ __forceinline__ void band_core(
    const float* __restrict__ f1base,      // f1 + (b*256 + cq*64)*4096 + lane
    const float2 (* __restrict__ sw)[72],  // this wave's 32 padded channel-pair rows
    int ty, int dy0, int lane,
    float acc[3][PATCH])
{
    int yoff[ND];                          // clamped; invalid rows discarded at merge
#pragma unroll
    for (int i = 0; i < ND; ++i) {
        int y = ty + dy0 + i - MD;
        y = y < 0 ? 0 : (y > 63 ? 63 : y);
        yoff[i] = y * 64;
    }

#pragma unroll 2
    for (int cp = 0; cp < 32; ++cp) {      // channel pair: channels 2cp, 2cp+1 of this quarter
        const float* c0 = f1base + (size_t)(2 * cp) * 4096;
        float f1v0[ND], f1v1[ND];
#pragma unroll
        for (int i = 0; i < ND; ++i) {
            f1v0[i] = c0[yoff[i]];                    // batched coalesced global loads
            f1v1[i] = c0[4096 + yoff[i]];
        }
        const float2* wp = &sw[cp][lane];
        float2 sh2[PATCH];
#pragma unroll
        for (int dxi = 0; dxi < PATCH; ++dxi)
            sh2[dxi] = wp[8 - dxi];                   // ds_read_b64: 2 channels per read
#pragma unroll
        for (int i = 0; i < ND; ++i)
#pragma unroll
            for (int dxi = 0; dxi < PATCH; ++dxi) {
                acc[i][dxi] = fmaf(f1v0[i], sh2[dxi].x, acc[i][dxi]);
                acc[i][dxi] = fmaf(f1v1[i], sh2[dxi].y, acc[i][dxi]);
            }
    }
}

__global__ __launch_bounds__(BT, 8) void cv_kernel(
    const float* __restrict__ f1,
    const float* __restrict__ f2,
    float* __restrict__ out)
{
    const int tid = threadIdx.x;

    // ---------------- zero-streaming blocks ----------------
    if (blockIdx.x >= NBAND) {
        // float4 index i: bits [0:4)=x4, [4:10)=y, [10:16)=tx, [16:22)=ty, [22:24)=b
        float4* o4 = (float4*)out;
        const float4 z4 = make_float4(0.f, 0.f, 0.f, 0.f);
        const int total4 = 4 * 4096 * 64 * 16;            // 16,777,216
        const int stride = NZERO * BT;
        for (int i = (blockIdx.x - NBAND) * BT + tid; i < total4; i += stride) {
            int y  = (i >> 4) & 63;
            int ty = (i >> 16) & 63;
            int dy = y - ty;
            if (dy < -MD || dy > MD)
                o4[i] = z4;
        }
        return;
    }

    // ---------------- band-compute blocks ----------------
    const int bty = blockIdx.x;       // 0..255
    const int b   = bty >> 6;
    const int ty  = bty & 63;
    const int lane = tid & 63;        // u = x position
    const int w    = tid >> 6;        // 0..15
    const int cq   = w >> 2;          // channel quarter
    const int dyg  = w & 3;           // dy group: rows {0,1}/{2,3}/{4,5}/{6,7,8}
    const int dy0  = dyg * 2;
    const int nd   = (dyg == 3) ? 3 : 2;

    __shared__ float uLds[128 * 72 * 2];   // 73,728 B: sF2[128][72] float2, sVals[64][81] after
    float2 (*sF2)[72] = (float2(*)[72])uLds;

    // margins: every thread zeroes one float2 -> p in {0,1,2,3,68,69,70,71} per pair-row
    {
        int c2 = tid >> 3, slot = tid & 7;
        int p  = slot < 4 ? slot : 64 + slot;
        sF2[c2][p] = make_float2(0.f, 0.f);
    }
    // main staging: e = m*1024+tid -> c2 = e>>5 (pair row), x2 = e&31 (two x per thread)
    const float* f2b = f2 + (size_t)(b * 256) * 4096 + ty * 64;
#pragma unroll
    for (int m = 0; m < 4; ++m) {
        int e  = m * BT + tid;        // 0..4095
        int c2 = e >> 5, x2 = e & 31;
        const float2* r0 = (const float2*)(f2b + (size_t)(2 * c2) * 4096);
        const float2* r1 = (const float2*)(f2b + (size_t)(2 * c2 + 1) * 4096);
        float2 g0 = r0[x2];           // f2[2c2][2x2], f2[2c2][2x2+1]  (coalesced)
        float2 g1 = r1[x2];
        *(float4*)&sF2[c2][4 + 2 * x2] = make_float4(g0.x, g1.x, g0.y, g1.y);  // 16B-aligned
    }
    __syncthreads();

    float acc[3][PATCH];
#pragma unroll
    for (int i = 0; i < 3; ++i)
#pragma unroll
        for (int j = 0; j < PATCH; ++j) acc[i][j] = 0.f;

    const float* f1b = f1 + (size_t)(b * 256 + cq * 64) * 4096 + lane;
    const float2 (*sw)[72] = &sF2[cq * 32];

    if (dyg == 3) band_core<3>(f1b, sw, ty, dy0, lane, acc);
    else          band_core<2>(f1b, sw, ty, dy0, lane, acc);

    __syncthreads();                  // all sF2 reads complete; uLds becomes sVals
    float (*sVals)[81] = (float(*)[81])uLds;   // sVals[tx][dyi*9+dxi]

    // Merge without zero-fill: cq==0 waves cover every read entry exactly once -> store.
    if (cq == 0) {
#pragma unroll
        for (int i = 0; i < 3; ++i) {
            if (i >= nd) continue;    // wave-uniform
            int dyi = dy0 + i;
            int y = ty + dyi - MD;
            if ((unsigned)y >= 64u) continue;
#pragma unroll
            for (int dxi = 0; dxi < PATCH; ++dxi) {
                int tx = lane - (dxi - MD);
                if ((unsigned)tx < 64u)
                    sVals[tx][dyi * PATCH + dxi] = acc[i][dxi];   // stride 81: conflict-free
            }
        }
    }
    __syncthreads();
    if (cq != 0) {
#pragma unroll
        for (int i = 0; i < 3; ++i) {
            if (i >= nd) continue;
            int dyi = dy0 + i;
            int y = ty + dyi - MD;
            if ((unsigned)y >= 64u) continue;
#pragma unroll
            for (int dxi = 0; dxi < PATCH; ++dxi) {
                int tx = lane - (dxi - MD);
                if ((unsigned)tx < 64u)
                    atomicAdd(&sVals[tx][dyi * PATCH + dxi], acc[i][dxi]);
            }
        }
    }
    __syncthreads();

    // Band rows: full 64-float rows (9-wide value window, zeros elsewhere).
    float4* out4 = (float4*)(out + (size_t)(b * 4096 + ty * 64) * 4096);
    const int q4 = tid & 15;          // float4 index within a row
    const int ro = tid >> 4;          // 0..63
    for (int rb = 0; rb < 64 * PATCH; rb += 64) {
        int row = rb + ro;            // row = tx*9 + dyi
        int tx  = row / PATCH;        // const divisor -> magic multiply
        int dyi = row - tx * PATCH;
        int y   = ty + dyi - MD;
        if ((unsigned)y < 64u) {
            float comp[4];
#pragma unroll
            for (int j = 0; j < 4; ++j) {
                int x  = q4 * 4 + j;
                int dx = x - tx;
                comp[j] = (dx >= -MD && dx <= MD) ? sVals[tx][dyi * PATCH + dx + MD] : 0.f;
            }
            out4[tx * 1024 + y * 16 + q4] = make_float4(comp[0], comp[1], comp[2], comp[3]);
        }
    }
}

extern "C" void kernel_launch(void* const* d_in, const int* in_sizes, int n_in,
                              void* d_out, int out_size, void* d_ws, size_t ws_size,
                              hipStream_t stream) {
    const float* f1 = (const float*)d_in[0];
    const float* f2 = (const float*)d_in[1];
    float* out = (float*)d_out;
    cv_kernel<<<NBAND + NZERO, BT, 0, stream>>>(f1, f2, out);
}

// Round 16
// 85.918 us; speedup vs baseline: 1.3096x; 1.3096x over previous
//
#include <hip/hip_runtime.h>

// Problem constants
#define MD 4
#define PATCH 9          // 2*MD+1
#define NBAND 256        // band-compute blocks: (b, ty) = 4 * 64
#define NZERO 2048       // zero-streaming blocks
#define BT 512           // threads per block (8 waves)
// feat1/feat2: (4, 256, 64, 64) fp32
// out: (4, 4096, 64, 64) fp32 = 256 MB
//
// out[b, ty*64+tx, y, x] = sum_c f1[b,c,y,x] * f2[b,c,ty,tx]  if |ty-y|<=4 && |tx-x|<=4, else 0.
//
// R16 = R11 structure with f2 staged as BF16 CHANNEL-PAIRS packed in u32:
//   sF2[c2][p] = bf16(f2[2c2+1][p-4])<<16 | bf16(f2[2c2][p-4]), 4-slot zero margins.
//   9-wide window read = 9 ds_read_b32 serving TWO channels each -> halves per-wave LDS
//   instruction count (R11's band was LDS-issue-bound) at only 9 VGPRs for the window
//   (R15's float2 version needed 18 -> spilled at the 64-VGPR cap -> regressed).
//   LDS = 36.9 KB -> with 512-thr blocks, 4 blocks/CU (1 band + 3 zero co-resident):
//   zero-stream drains at near-full rate under the band phase.
// Precision: bf16 f2 x fp32 f1, fp32 accum -> abs err ~0.06 << 1.6 threshold.

__device__ __forceinline__ unsigned bf16b(float x)   // f32 -> bf16 bits (RNE)
{
    unsigned u = __float_as_uint(x);
    return (u + 0x7fffu + ((u >> 16) & 1u)) >> 16;
}

template<int ND>
__device__ __forceinline__ void band_core(
    const float* __restrict__ f1base,          // f1 + (b*256 + cq*128)*4096 + lane
    const unsigned (* __restrict__ sw)[72],    // this wave's 64 padded channel-pair rows
    int ty, int dy0, int lane,
    float acc[3][PATCH])
{
    int yoff[ND];                          // clamped; invalid rows discarded at merge
#pragma unroll
    for (int i = 0; i < ND; ++i) {
        int y = ty + dy0 + i - MD;
        y = y < 0 ? 0 : (y > 63 ? 63 : y);
        yoff[i] = y * 64;
    }

#pragma unroll 2
    for (int cp = 0; cp < 64; ++cp) {      // channel pair: channels 2cp, 2cp+1 of this half
        const float* c0 = f1base + (size_t)(2 * cp) * 4096;
        float f1v0[ND], f1v1[ND];
#pragma unroll
        for (int i = 0; i < ND; ++i) {
            f1v0[i] = c0[yoff[i]];                    // batched coalesced global loads
            f1v1[i] = c0[4096 + yoff[i]];
        }
        const unsigned* wp = &sw[cp][lane];
        unsigned sh2[PATCH];
#pragma unroll
        for (int dxi = 0; dxi < PATCH; ++dxi)
            sh2[dxi] = wp[8 - dxi];                   // ds_read_b32: 2 channels per read
#pragma unroll
        for (int dxi = 0; dxi < PATCH; ++dxi) {
            float lo = __uint_as_float(sh2[dxi] << 16);          // channel 2cp
            float hi = __uint_as_float(sh2[dxi] & 0xffff0000u);  // channel 2cp+1
#pragma unroll
            for (int i = 0; i < ND; ++i) {
                acc[i][dxi] = fmaf(f1v0[i], lo, acc[i][dxi]);
                acc[i][dxi] = fmaf(f1v1[i], hi, acc[i][dxi]);
            }
        }
    }
}

__global__ __launch_bounds__(BT, 8) void cv_kernel(
    const float* __restrict__ f1,
    const float* __restrict__ f2,
    float* __restrict__ out)
{
    const int tid = threadIdx.x;

    // ---------------- zero-streaming blocks ----------------
    if (blockIdx.x >= NBAND) {
        // float4 index i: bits [0:4)=x4, [4:10)=y, [10:16)=tx, [16:22)=ty, [22:24)=b
        float4* o4 = (float4*)out;
        const float4 z4 = make_float4(0.f, 0.f, 0.f, 0.f);
        const int total4 = 4 * 4096 * 64 * 16;            // 16,777,216
        const int stride = NZERO * BT;
        for (int i = (blockIdx.x - NBAND) * BT + tid; i < total4; i += stride) {
            int y  = (i >> 4) & 63;
            int ty = (i >> 16) & 63;
            int dy = y - ty;
            if (dy < -MD || dy > MD)
                o4[i] = z4;
        }
        return;
    }

    // ---------------- band-compute blocks ----------------
    const int bty = blockIdx.x;       // 0..255
    const int b   = bty >> 6;
    const int ty  = bty & 63;
    const int lane = tid & 63;        // u = x position
    const int w    = tid >> 6;        // 0..7
    const int cq   = w >> 2;          // channel half (128 ch each)
    const int dyg  = w & 3;           // dy group: rows {0,1}/{2,3}/{4,5}/{6,7,8}
    const int dy0  = dyg * 2;
    const int nd   = (dyg == 3) ? 3 : 2;

    __shared__ unsigned uLds[128 * 72];    // 36,864 B: sF2[128][72] u32-pairs, sVals after
    unsigned (*sF2)[72] = (unsigned(*)[72])uLds;

    // zero the 4-slot margins: p in {0,1,2,3,68,69,70,71} per pair-row
    for (int i = tid; i < 128 * 8; i += BT) {
        int c2 = i >> 3, s = i & 7;
        sF2[c2][s < 4 ? s : 64 + s] = 0u;
    }
    // main staging: e -> c2 = e>>6 (pair row), x = e&63; coalesced f32 reads, u32 writes
    const float* f2b = f2 + (size_t)(b * 256) * 4096 + ty * 64;
#pragma unroll
    for (int m = 0; m < 16; ++m) {
        int e  = m * BT + tid;        // 0..8191
        int c2 = e >> 6, x = e & 63;
        float lo = f2b[(size_t)(2 * c2) * 4096 + x];
        float hi = f2b[(size_t)(2 * c2 + 1) * 4096 + x];
        sF2[c2][4 + x] = (bf16b(hi) << 16) | bf16b(lo);
    }
    __syncthreads();

    float acc[3][PATCH];
#pragma unroll
    for (int i = 0; i < 3; ++i)
#pragma unroll
        for (int j = 0; j < PATCH; ++j) acc[i][j] = 0.f;

    const float* f1b = f1 + (size_t)(b * 256 + cq * 128) * 4096 + lane;
    const unsigned (*sw)[72] = &sF2[cq * 64];

    if (dyg == 3) band_core<3>(f1b, sw, ty, dy0, lane, acc);
    else          band_core<2>(f1b, sw, ty, dy0, lane, acc);

    __syncthreads();                  // all sF2 reads complete; uLds becomes sVals
    float (*sVals)[81] = (float(*)[81])uLds;   // sVals[tx][dyi*9+dxi]

    // Merge without zero-fill: cq==0 waves cover every read entry exactly once -> store.
    if (cq == 0) {
#pragma unroll
        for (int i = 0; i < 3; ++i) {
            if (i >= nd) continue;    // wave-uniform
            int dyi = dy0 + i;
            int y = ty + dyi - MD;
            if ((unsigned)y >= 64u) continue;
#pragma unroll
            for (int dxi = 0; dxi < PATCH; ++dxi) {
                int tx = lane - (dxi - MD);
                if ((unsigned)tx < 64u)
                    sVals[tx][dyi * PATCH + dxi] = acc[i][dxi];   // stride 81: conflict-free
            }
        }
    }
    __syncthreads();
    if (cq != 0) {
#pragma unroll
        for (int i = 0; i < 3; ++i) {
            if (i >= nd) continue;
            int dyi = dy0 + i;
            int y = ty + dyi - MD;
            if ((unsigned)y >= 64u) continue;
#pragma unroll
            for (int dxi = 0; dxi < PATCH; ++dxi) {
                int tx = lane - (dxi - MD);
                if ((unsigned)tx < 64u)
                    atomicAdd(&sVals[tx][dyi * PATCH + dxi], acc[i][dxi]);
            }
        }
    }
    __syncthreads();

    // Band rows: full 64-float rows (9-wide value window, zeros elsewhere).
    float4* out4 = (float4*)(out + (size_t)(b * 4096 + ty * 64) * 4096);
    const int q4 = tid & 15;          // float4 index within a row
    const int ro = tid >> 4;          // 0..31
    for (int rb = 0; rb < 64 * PATCH; rb += 32) {
        int row = rb + ro;            // row = tx*9 + dyi
        int tx  = row / PATCH;        // const divisor -> magic multiply
        int dyi = row - tx * PATCH;
        int y   = ty + dyi - MD;
        if ((unsigned)y < 64u) {
            float comp[4];
#pragma unroll
            for (int j = 0; j < 4; ++j) {
                int x  = q4 * 4 + j;
                int dx = x - tx;
                comp[j] = (dx >= -MD && dx <= MD) ? sVals[tx][dyi * PATCH + dx + MD] : 0.f;
            }
            out4[tx * 1024 + y * 16 + q4] = make_float4(comp[0], comp[1], comp[2], comp[3]);
        }
    }
}

extern "C" void kernel_launch(void* const* d_in, const int* in_sizes, int n_in,
                              void* d_out, int out_size, void* d_ws, size_t ws_size,
                              hipStream_t stream) {
    const float* f1 = (const float*)d_in[0];
    const float* f2 = (const float*)d_in[1];
    float* out = (float*)d_out;
    cv_kernel<<<NBAND + NZERO, BT, 0, stream>>>(f1, f2, out);
}